// Round 8
// baseline (124.983 us; speedup 1.0000x reference)
//
#include <hip/hip_runtime.h>

// CapsuleNetwork routing, fused, one block per batch. B=2048, S=200, D=64, K=4.
//
// hat[b,k,s,:] = emb[b,s,:] @ W_k + b_k is never materialized:
//   logits[k,s] = emb[s]·u[k] + off[k],  u[k] = W_k @ G[k], off[k] = b_k·G[k]
//   v[k]        = e[k] @ W_k + ts[k]·b_k, e[k] = sum_s sw[k,s] emb[s]
// G = running sum of interests (cw telescopes).
//
// Round-8 = round-4 memory structure (full 200-row staging, 2 blocks/CU —
// rounds 5-7 proved 3-blocks/CU thrashes L2 and sidxs-compaction adds a
// dependent-load chain for a net loss) + latency surgery:
//  - barriers 17 -> 10: separate ssw/pe arrays (no pool union -> no mid-D
//    barrier); phase A + soff folded into E tail (same-wave LDS w->r).
//  - merged one-phase E on waves 0-3 with wreg[64] (full W column in regs).
//  - phase B 2-lane split: 400 threads active, 8 chunk-iters + 1 shfl_xor.
//  - it0 handled by ssw = 0.25*mask init (single generic D path).

#define NB 2048
#define NS 200
#define ND 64
#define NK 4
#define NT 512

__device__ __forceinline__ float wred64(float v) {
#pragma unroll
  for (int o = 1; o < 64; o <<= 1) v += __shfl_xor(v, o, 64);
  return v;
}

__device__ __forceinline__ void gload16(const float* g_, float* l_) {
  __builtin_amdgcn_global_load_lds(
      (const __attribute__((address_space(1))) unsigned int*)g_,
      (__attribute__((address_space(3))) unsigned int*)l_, 16, 0, 0);
}

#define RED_GRP(v) v += __shfl_xor(v, 16, 64); v += __shfl_xor(v, 32, 64);

__global__ __launch_bounds__(NT, 4) void caps_kernel(
    const float* __restrict__ his, const float* __restrict__ itemeb,
    const int* __restrict__ mask, const float* __restrict__ W,
    const float* __restrict__ bias, float* __restrict__ out) {
  __shared__ float semb[NS * ND];  // 51200B: row s, chunk c at slot (c+s)&15
  __shared__ float ssw[NS * NK];   // 3200B: sw[s][k] (it0: 0.25*mask)
  __shared__ float pe[8][NK][ND];  // 8192B: per-wave D partials; [0] = stash
  __shared__ float sG[NK][ND];     // 1024B: running interest sum
  __shared__ float su[NK][ND];     // 1024B: u[k] (also E's se bounce)
  __shared__ float pts[8][NK];     // 128B
  __shared__ float soff[NK], satt[NK];
  __shared__ int sidx;
  // total 64804 B -> 2 blocks/CU

  const int t = threadIdx.x;
  const int w = t >> 6, l = t & 63;
  const int g = l >> 4, j = l & 15;  // 16-lane group / chunk
  const int gid = (w << 2) | g;      // 0..31
  const int b = blockIdx.x;
  const float* eb = his + (size_t)b * NS * ND;

  // ---- full W column in regs for E: wave k owns W[0..64)[64k+l] ----
  const int ke = w & 3;
  float wreg[64];
  if (w < 4) {
#pragma unroll
    for (int c = 0; c < 64; ++c)
      wreg[c] = W[(size_t)c * (NK * ND) + ke * ND + l];
  }
  float breg = bias[ke * ND + l];
  float iq = itemeb[(size_t)b * ND + l];

  // ---- stage all 200 rows (round-4 addresses: linear dest, rotated src) ----
  for (int i = w; i < 50; i += 8) {
    int s = 4 * i + g;
    int q = (j - s) & 15;  // global chunk that lands at slot j
    gload16(eb + (s << 6) + (q << 2), &semb[i * 256]);
  }
  // ---- ssw init = softmax(0) over k, masked = 0.25*mask ----
  if (t < NS) {
    float m = (mask[b * NS + t] != 0) ? 0.25f : 0.0f;
    *(float4*)&ssw[t * 4] = make_float4(m, m, m, m);
  }
  __syncthreads();

  for (int it = 0; it < 3; ++it) {
    if (it > 0) {
      // ---- B: 2 lanes per row; 8 chunk-iters each; shfl_xor(1) combine ----
      const int row = t >> 1, p = t & 1;
      if (row < NS) {
        float lg0 = 0.f, lg1 = 0.f, lg2 = 0.f, lg3 = 0.f;
#pragma unroll
        for (int cc = 0; cc < 8; ++cc) {
          int jj = 8 * p + cc;
          float4 eq = *(const float4*)&semb[(row << 6) + 4 * ((jj + row) & 15)];
          float4 u0 = *(const float4*)&su[0][4 * jj];  // 2-addr broadcast
          float4 u1 = *(const float4*)&su[1][4 * jj];
          float4 u2 = *(const float4*)&su[2][4 * jj];
          float4 u3 = *(const float4*)&su[3][4 * jj];
          lg0 += eq.x * u0.x + eq.y * u0.y + eq.z * u0.z + eq.w * u0.w;
          lg1 += eq.x * u1.x + eq.y * u1.y + eq.z * u1.z + eq.w * u1.w;
          lg2 += eq.x * u2.x + eq.y * u2.y + eq.z * u2.z + eq.w * u2.w;
          lg3 += eq.x * u3.x + eq.y * u3.y + eq.z * u3.z + eq.w * u3.w;
        }
        lg0 += __shfl_xor(lg0, 1, 64);
        lg1 += __shfl_xor(lg1, 1, 64);
        lg2 += __shfl_xor(lg2, 1, 64);
        lg3 += __shfl_xor(lg3, 1, 64);
        lg0 += soff[0]; lg1 += soff[1]; lg2 += soff[2]; lg3 += soff[3];
        float mx = fmaxf(fmaxf(lg0, lg1), fmaxf(lg2, lg3));
        float e0 = __expf(lg0 - mx), e1 = __expf(lg1 - mx);
        float e2 = __expf(lg2 - mx), e3 = __expf(lg3 - mx);
        float mv = (mask[(size_t)b * NS + row] != 0) ? 1.0f : 0.0f;
        float r = mv / (e0 + e1 + e2 + e3);
        if (p == 0)
          *(float4*)&ssw[row * 4] = make_float4(e0 * r, e1 * r, e2 * r, e3 * r);
      }
      __syncthreads();
    }

    // ---- D: group gid sweeps rows s = gid + 32*tt ----
    float4 a0 = {0, 0, 0, 0}, a1 = {0, 0, 0, 0}, a2 = {0, 0, 0, 0},
           a3 = {0, 0, 0, 0};
    float t0 = 0, t1 = 0, t2 = 0, t3 = 0;
    const int ntr = (w < 2) ? 7 : 6;  // wave-uniform trip count
    for (int tt = 0; tt < ntr; ++tt) {
      int s = gid + 32 * tt;
      float4 eq = *(const float4*)&semb[(s << 6) + 4 * ((j + s) & 15)];
      float4 s4 = *(const float4*)&ssw[s * 4];  // broadcast
      a0.x += s4.x * eq.x; a0.y += s4.x * eq.y; a0.z += s4.x * eq.z; a0.w += s4.x * eq.w;
      a1.x += s4.y * eq.x; a1.y += s4.y * eq.y; a1.z += s4.y * eq.z; a1.w += s4.y * eq.w;
      a2.x += s4.z * eq.x; a2.y += s4.z * eq.y; a2.z += s4.z * eq.z; a2.w += s4.z * eq.w;
      a3.x += s4.w * eq.x; a3.y += s4.w * eq.y; a3.z += s4.w * eq.z; a3.w += s4.w * eq.w;
      t0 += s4.x; t1 += s4.y; t2 += s4.z; t3 += s4.w;
    }
    RED_GRP(a0.x) RED_GRP(a0.y) RED_GRP(a0.z) RED_GRP(a0.w)
    RED_GRP(a1.x) RED_GRP(a1.y) RED_GRP(a1.z) RED_GRP(a1.w)
    RED_GRP(a2.x) RED_GRP(a2.y) RED_GRP(a2.z) RED_GRP(a2.w)
    RED_GRP(a3.x) RED_GRP(a3.y) RED_GRP(a3.z) RED_GRP(a3.w)
    RED_GRP(t0) RED_GRP(t1) RED_GRP(t2) RED_GRP(t3)
    if (l < 16) {
      *(float4*)&pe[w][0][4 * l] = a0;
      *(float4*)&pe[w][1][4 * l] = a1;
      *(float4*)&pe[w][2][4 * l] = a2;
      *(float4*)&pe[w][3][4 * l] = a3;
    }
    if (l == 0) { pts[w][0] = t0; pts[w][1] = t1; pts[w][2] = t2; pts[w][3] = t3; }
    __syncthreads();

    // ---- E (waves 0-3, k = w): reduce pe, dot wreg, squash, fold A ----
    if (w < 4) {
      float sse = 0.f;
#pragma unroll
      for (int w2 = 0; w2 < 8; ++w2) sse += pe[w2][ke][l];
      su[ke][l] = sse;  // temp bounce: same-wave write -> broadcast read
      float ts_ = 0.f;
#pragma unroll
      for (int w2 = 0; w2 < 8; ++w2) ts_ += pts[w2][ke];
      float vp = ts_ * breg;
#pragma unroll
      for (int q2 = 0; q2 < 16; ++q2) {
        float4 e4 = *(const float4*)&su[ke][4 * q2];  // broadcast
        vp += e4.x * wreg[4 * q2 + 0] + e4.y * wreg[4 * q2 + 1] +
              e4.z * wreg[4 * q2 + 2] + e4.w * wreg[4 * q2 + 3];
      }
      float n2 = wred64(vp * vp);
      float scale = n2 / (1.f + n2) / sqrtf(n2 + 1e-9f);
      float inter = scale * vp;
      if (it < 2) {
        float gnew = (it == 0) ? inter : (sG[ke][l] + inter);
        sG[ke][l] = gnew;
        float ob = wred64(breg * gnew);
        if (l == 0) soff[ke] = ob;
        // A-fold: su[k][l] = W-row-l (cols 64k..) . G[k]  (overwrites temp)
        const float4* Wr = (const float4*)(W + (size_t)l * (NK * ND) + ke * ND);
        const float4* Gk = (const float4*)&sG[ke][0];  // same-wave broadcast
        float a = 0.f;
#pragma unroll
        for (int d4 = 0; d4 < 16; ++d4) {
          float4 wv = Wr[d4], gv = Gk[d4];
          a += wv.x * gv.x + wv.y * gv.y + wv.z * gv.z + wv.w * gv.w;
        }
        su[ke][l] = a;
      } else {
        out[((size_t)b * NK + ke) * ND + l] = inter;
        float dot_ = wred64(inter * iq);
        pe[0][ke][l] = inter;  // stash for argmax gather (pe dead)
        if (l == 0) satt[ke] = dot_;
      }
    }
    __syncthreads();
  }

  // ---- readout: first-max argmax (== np.argmax) + gather ----
  if (t == 0) {
    int bi = 0;
    float bv = satt[0];
#pragma unroll
    for (int kk = 1; kk < NK; ++kk)
      if (satt[kk] > bv) { bv = satt[kk]; bi = kk; }
    sidx = bi;
  }
  __syncthreads();
  if (t < ND) out[(size_t)NB * NK * ND + (size_t)b * ND + t] = pe[0][sidx][t];
}

extern "C" void kernel_launch(void* const* d_in, const int* in_sizes, int n_in,
                              void* d_out, int out_size, void* d_ws, size_t ws_size,
                              hipStream_t stream) {
  (void)in_sizes; (void)n_in; (void)out_size; (void)d_ws; (void)ws_size;
  const float* his = (const float*)d_in[0];
  const float* itemeb = (const float*)d_in[1];
  const int* mask = (const int*)d_in[2];
  const float* W = (const float*)d_in[3];
  const float* bias = (const float*)d_in[4];
  float* out = (float*)d_out;
  caps_kernel<<<NB, NT, 0, stream>>>(his, itemeb, mask, W, bias, out);
}

// Round 9
// 92.235 us; speedup vs baseline: 1.3550x; 1.3550x over previous
//
#include <hip/hip_runtime.h>

// CapsuleNetwork routing, fused, one block per batch. B=2048, S=200, D=64, K=4.
//
// hat[b,k,s,:] = emb[b,s,:] @ W_k + b_k is never materialized:
//   logits[k,s] = emb[s]·u[k] + off[k],  u[k] = W_k @ G[k], off[k] = b_k·G[k]
//   v[k]        = e[k] @ W_k + ts[k]·b_k, e[k] = sum_s sw[k,s] emb[s]
// G = running sum of interests (cw telescopes).
//
// Round-9 = round-4 proven core (full 200-row linear staging, 2 blocks/CU,
// wreg[32] h-split E — round 8's wreg[64] SPILLED at the 64-VGPR cap) +
//  - B 2-lane split (400 threads, 8 chunks + 1 shfl_xor)
//  - separate ssw/pe (no union barrier); pv lives in ssw[0..255]
//  - A + soff folded into E2 (A depends on G, so same dependency, one less
//    phase+barrier; proven r6/r7)
//  - rot(s)=(s+(s>>3))&15: old s&15 gave Δrow=8 identical bank-starts
//    (8-way B conflicts); new rot spreads them. D/staging rot-invariant.

#define NB 2048
#define NS 200
#define ND 64
#define NK 4
#define NT 512

__device__ __forceinline__ float wred64(float v) {
#pragma unroll
  for (int o = 1; o < 64; o <<= 1) v += __shfl_xor(v, o, 64);
  return v;
}

__device__ __forceinline__ int rot(int s) { return (s + (s >> 3)) & 15; }

__device__ __forceinline__ void gload16(const float* g_, float* l_) {
  __builtin_amdgcn_global_load_lds(
      (const __attribute__((address_space(1))) unsigned int*)g_,
      (__attribute__((address_space(3))) unsigned int*)l_, 16, 0, 0);
}

#define RED_GRP(v) v += __shfl_xor(v, 16, 64); v += __shfl_xor(v, 32, 64);

__global__ __launch_bounds__(NT, 4) void caps_kernel(
    const float* __restrict__ his, const float* __restrict__ itemeb,
    const int* __restrict__ mask, const float* __restrict__ W,
    const float* __restrict__ bias, float* __restrict__ out) {
  __shared__ float semb[NS * ND];  // 51200B: row s, chunk c at slot (c+rot(s))&15
  __shared__ float ssw[NS * NK];   // 3200B: sw[s][k]; [0..255] doubles as pv
  __shared__ float pe[8][NK][ND];  // 8192B: D partials; pe[0] = interest stash
  __shared__ float sG[NK][ND];     // 1024B: running interest sum
  __shared__ float su[NK][ND];     // 1024B: u[k]; E1 se-bounce
  __shared__ float pts[8][NK];     // 128B
  __shared__ float soff[NK], satt[NK];
  __shared__ int sidx;
  // total 64804 B -> 2 blocks/CU

  const int t = threadIdx.x;
  const int w = t >> 6, l = t & 63;
  const int g = l >> 4, j = l & 15;  // 16-lane group / chunk
  const int gid = (w << 2) | g;      // 0..31
  const int ke = w & 3, h_ = w >> 2; // E roles
  const int b = blockIdx.x;
  const float* eb = his + (size_t)b * NS * ND;

  // ---- W slice in regs: wave (ke,h) owns W[32h..32h+32)[64ke+l] ----
  float wreg[32];
#pragma unroll
  for (int c = 0; c < 32; ++c)
    wreg[c] = W[(size_t)(32 * h_ + c) * (NK * ND) + ke * ND + l];
  float breg = bias[ke * ND + l];
  float iq = itemeb[(size_t)b * ND + l];

  // ---- stage all 200 rows (linear LDS dest, rotated global source) ----
  for (int i = w; i < 50; i += 8) {
    int s = 4 * i + g;
    int q = (j - rot(s)) & 15;  // global chunk that lands at slot j
    gload16(eb + (s << 6) + (q << 2), &semb[i * 256]);
  }
  // ---- ssw init = softmax(0) over k, masked = 0.25*mask ----
  if (t < NS) {
    float m = (mask[(size_t)b * NS + t] != 0) ? 0.25f : 0.0f;
    *(float4*)&ssw[t * 4] = make_float4(m, m, m, m);
  }
  __syncthreads();

  for (int it = 0; it < 3; ++it) {
    if (it > 0) {
      // ---- B: 2 lanes per row; 8 chunk-iters; shfl_xor(1) combine ----
      const int row = t >> 1, p = t & 1;
      if (row < NS) {
        const int rr = rot(row);
        float lg0 = 0.f, lg1 = 0.f, lg2 = 0.f, lg3 = 0.f;
#pragma unroll
        for (int cc = 0; cc < 8; ++cc) {
          int jj = 8 * p + cc;
          float4 eq = *(const float4*)&semb[(row << 6) + 4 * ((jj + rr) & 15)];
          float4 u0 = *(const float4*)&su[0][4 * jj];  // 2-addr broadcast
          float4 u1 = *(const float4*)&su[1][4 * jj];
          float4 u2 = *(const float4*)&su[2][4 * jj];
          float4 u3 = *(const float4*)&su[3][4 * jj];
          lg0 += eq.x * u0.x + eq.y * u0.y + eq.z * u0.z + eq.w * u0.w;
          lg1 += eq.x * u1.x + eq.y * u1.y + eq.z * u1.z + eq.w * u1.w;
          lg2 += eq.x * u2.x + eq.y * u2.y + eq.z * u2.z + eq.w * u2.w;
          lg3 += eq.x * u3.x + eq.y * u3.y + eq.z * u3.z + eq.w * u3.w;
        }
        lg0 += __shfl_xor(lg0, 1, 64);
        lg1 += __shfl_xor(lg1, 1, 64);
        lg2 += __shfl_xor(lg2, 1, 64);
        lg3 += __shfl_xor(lg3, 1, 64);
        lg0 += soff[0]; lg1 += soff[1]; lg2 += soff[2]; lg3 += soff[3];
        float mx = fmaxf(fmaxf(lg0, lg1), fmaxf(lg2, lg3));
        float e0 = __expf(lg0 - mx), e1 = __expf(lg1 - mx);
        float e2 = __expf(lg2 - mx), e3 = __expf(lg3 - mx);
        float mv = (mask[(size_t)b * NS + row] != 0) ? 1.0f : 0.0f;
        float r = mv / (e0 + e1 + e2 + e3);
        if (p == 0)
          *(float4*)&ssw[row * 4] = make_float4(e0 * r, e1 * r, e2 * r, e3 * r);
      }
      __syncthreads();
    }

    // ---- D: group gid sweeps rows s = gid + 32*tt (wave-uniform trips) ----
    float4 a0 = {0, 0, 0, 0}, a1 = {0, 0, 0, 0}, a2 = {0, 0, 0, 0},
           a3 = {0, 0, 0, 0};
    float t0 = 0, t1 = 0, t2 = 0, t3 = 0;
    const int ntr = (w < 2) ? 7 : 6;
    for (int tt = 0; tt < ntr; ++tt) {
      int s = gid + 32 * tt;
      float4 eq = *(const float4*)&semb[(s << 6) + 4 * ((j + rot(s)) & 15)];
      float4 s4 = *(const float4*)&ssw[s * 4];  // broadcast
      a0.x += s4.x * eq.x; a0.y += s4.x * eq.y; a0.z += s4.x * eq.z; a0.w += s4.x * eq.w;
      a1.x += s4.y * eq.x; a1.y += s4.y * eq.y; a1.z += s4.y * eq.z; a1.w += s4.y * eq.w;
      a2.x += s4.z * eq.x; a2.y += s4.z * eq.y; a2.z += s4.z * eq.z; a2.w += s4.z * eq.w;
      a3.x += s4.w * eq.x; a3.y += s4.w * eq.y; a3.z += s4.w * eq.z; a3.w += s4.w * eq.w;
      t0 += s4.x; t1 += s4.y; t2 += s4.z; t3 += s4.w;
    }
    RED_GRP(a0.x) RED_GRP(a0.y) RED_GRP(a0.z) RED_GRP(a0.w)
    RED_GRP(a1.x) RED_GRP(a1.y) RED_GRP(a1.z) RED_GRP(a1.w)
    RED_GRP(a2.x) RED_GRP(a2.y) RED_GRP(a2.z) RED_GRP(a2.w)
    RED_GRP(a3.x) RED_GRP(a3.y) RED_GRP(a3.z) RED_GRP(a3.w)
    RED_GRP(t0) RED_GRP(t1) RED_GRP(t2) RED_GRP(t3)
    if (l < 16) {
      *(float4*)&pe[w][0][4 * l] = a0;
      *(float4*)&pe[w][1][4 * l] = a1;
      *(float4*)&pe[w][2][4 * l] = a2;
      *(float4*)&pe[w][3][4 * l] = a3;
    }
    if (l == 0) { pts[w][0] = t0; pts[w][1] = t1; pts[w][2] = t2; pts[w][3] = t3; }
    __syncthreads();

    // ---- E1 (all 8 waves): wave (ke,h) reduces its 32-col half of pe,
    //      dots with wreg; h=1 parks vp in ssw[0..255] ----
    {
      int cl = 32 * h_ + (l & 31);
      float sse = 0.f;
#pragma unroll
      for (int w2 = 0; w2 < 8; ++w2) sse += pe[w2][ke][cl];
      su[ke][cl] = sse;  // same-wave write -> broadcast read (own half only)
      float vp = 0.f;
#pragma unroll
      for (int q2 = 0; q2 < 8; ++q2) {
        float4 e4 = *(const float4*)&su[ke][32 * h_ + 4 * q2];  // broadcast
        vp += e4.x * wreg[4 * q2 + 0] + e4.y * wreg[4 * q2 + 1] +
              e4.z * wreg[4 * q2 + 2] + e4.w * wreg[4 * q2 + 3];
      }
      if (h_) ssw[ke * 64 + l] = vp;  // pv (ssw rewritten by next B / dead)
      __syncthreads();

      // ---- E2 (waves 0-3): combine, squash, update G, fold A+soff ----
      if (h_ == 0) {
        float ts_ = 0.f;
#pragma unroll
        for (int w2 = 0; w2 < 8; ++w2) ts_ += pts[w2][ke];
        float accv = vp + ssw[ke * 64 + l] + ts_ * breg;
        float n2 = wred64(accv * accv);
        float scale = n2 / (1.f + n2) / sqrtf(n2 + 1e-9f);
        float inter = scale * accv;
        if (it < 2) {
          float gnew = (it == 0) ? inter : (sG[ke][l] + inter);
          sG[ke][l] = gnew;
          float ob = wred64(breg * gnew);
          if (l == 0) soff[ke] = ob;
          // A-fold: su[k][l] = W-row-l (cols 64k..) . G[k]
          const float4* Wr =
              (const float4*)(W + (size_t)l * (NK * ND) + ke * ND);
          const float4* Gk = (const float4*)&sG[ke][0];  // same-wave broadcast
          float a = 0.f;
#pragma unroll
          for (int d4 = 0; d4 < 16; ++d4) {
            float4 wv = Wr[d4], gv = Gk[d4];
            a += wv.x * gv.x + wv.y * gv.y + wv.z * gv.z + wv.w * gv.w;
          }
          su[ke][l] = a;
        } else {
          out[((size_t)b * NK + ke) * ND + l] = inter;
          float dot_ = wred64(inter * iq);
          pe[0][ke][l] = inter;  // stash for argmax gather (pe dead)
          if (l == 0) satt[ke] = dot_;
        }
      }
      __syncthreads();
    }
  }

  // ---- readout: first-max argmax (== np.argmax) + gather ----
  if (t == 0) {
    int bi = 0;
    float bv = satt[0];
#pragma unroll
    for (int kk = 1; kk < NK; ++kk)
      if (satt[kk] > bv) { bv = satt[kk]; bi = kk; }
    sidx = bi;
  }
  __syncthreads();
  if (t < ND) out[(size_t)NB * NK * ND + (size_t)b * ND + t] = pe[0][sidx][t];
}

extern "C" void kernel_launch(void* const* d_in, const int* in_sizes, int n_in,
                              void* d_out, int out_size, void* d_ws, size_t ws_size,
                              hipStream_t stream) {
  (void)in_sizes; (void)n_in; (void)out_size; (void)d_ws; (void)ws_size;
  const float* his = (const float*)d_in[0];
  const float* itemeb = (const float*)d_in[1];
  const int* mask = (const int*)d_in[2];
  const float* W = (const float*)d_in[3];
  const float* bias = (const float*)d_in[4];
  float* out = (float*)d_out;
  caps_kernel<<<NB, NT, 0, stream>>>(his, itemeb, mask, W, bias, out);
}